// Round 8
// baseline (386.451 us; speedup 1.0000x reference)
//
#include <hip/hip_runtime.h>
#include <hip/hip_bf16.h>

// STSA R8: k_attn_s rebuilt for bank-optimal LDS + async K staging.
//  k_prep    : weights -> bf16.                              (unchanged)
//  k_fused_t : per (b,m): x->regs, 6 projections, temporal attn -> ot. (unchanged)
//  k_attn_s  : 1024 blocks x 4 waves; wave = (bm, head-pair). No mid-kernel
//              barriers. Per-wave 12.5KiB LDS: K slot-major double-buffer
//              (2 x 4KiB, filled by global_load_lds 16B: dst = base+lane*16),
//              V [64 key][72B-stride rows] (reg-staged, conflict-free u16 reads).
//              T14: issue K(c+1) async + V(c+1)->regs, compute(c), vmcnt(0),
//              ds_write V(c+1). Final O staged + block-coop full-line store.
//  k_comb    : outproj(ot)+outproj(os)+bias -> out.          (unchanged)
// Softmax scale folded into Q (0.25*log2e*0.5; 0.5 compensates hd=16 duplicated
// into both K-halves), exp2, no max-subtract, normalize at the end.

typedef __attribute__((ext_vector_type(8))) short bf16x8;
typedef __attribute__((ext_vector_type(4))) short short4v;
typedef __attribute__((ext_vector_type(4))) float f32x4;

#define DEVI static __device__ __forceinline__
#define MFMA(a, b, c) __builtin_amdgcn_mfma_f32_16x16x32_bf16(a, b, c, 0, 0, 0)

static constexpr float QSCALE = 0.25f * 1.44269504088896340736f * 0.5f;

DEVI short f2bfs(float f) {
  __hip_bfloat16 h = __float2bfloat16(f);
  return __builtin_bit_cast(short, h);
}

// 64 rows x 128 bf16 LDS tile, 256B rows, XOR swizzle on write AND read.
DEVI int swzb(int row, int colh) {
  return (row * 256 + colh * 2) ^ ((row & 7) << 4);
}

// generic pointer -> 32-bit LDS byte offset
DEVI unsigned ldsoff(const void* p) {
  return (unsigned)(unsigned long long)(__attribute__((address_space(3))) const void*)p;
}

// async global -> LDS, 16B per lane; LDS dst = ldsByte + lane*16 (wave-uniform base)
DEVI void gload16(const void* g, unsigned ldsByte) {
  __builtin_amdgcn_global_load_lds(
      (const __attribute__((address_space(1))) unsigned int*)g,
      (__attribute__((address_space(3))) unsigned int*)ldsByte, 16, 0, 0);
}

// ---------------------------------------------------------------- k_prep ----
__global__ void __launch_bounds__(256) k_prep(
    const float* __restrict__ twin, const float* __restrict__ tbin,
    const float* __restrict__ twout, const float* __restrict__ tbout,
    const float* __restrict__ swin, const float* __restrict__ sbin,
    const float* __restrict__ swout, const float* __restrict__ sbout,
    short* __restrict__ wcat, float* __restrict__ biasin,
    short* __restrict__ wto, short* __restrict__ wso, float* __restrict__ biasc) {
  const int stride = gridDim.x * 256;
  const int t0 = blockIdx.x * 256 + threadIdx.x;
  for (int i = t0; i < 768 * 128; i += stride) {
    float v = (i < 384 * 128) ? twin[i] : swin[i - 384 * 128];
    wcat[i] = f2bfs(v);
  }
  for (int i = t0; i < 128 * 128; i += stride) {
    wto[i] = f2bfs(twout[i]);
    wso[i] = f2bfs(swout[i]);
  }
  for (int i = t0; i < 768; i += stride)
    biasin[i] = (i < 384) ? tbin[i] : sbin[i - 384];
  for (int i = t0; i < 128; i += stride)
    biasc[i] = tbout[i] + sbout[i];
}

// --------------------------------------------------------------- helpers ----
DEVI void attn_block(const char* qbuf, const char* kbuf, const char* vbuf,
                     int w, int lo, int hi, int colq,
                     f32x4 (*o)[4], float (*ls)[4]) {
  const f32x4 zf = {0.f, 0.f, 0.f, 0.f};
#pragma unroll
  for (int hh = 0; hh < 2; ++hh) {
    const int hc = (2 * w + hh) * 16;
    bf16x8 qf[4];
#pragma unroll
    for (int qt = 0; qt < 4; ++qt)
      qf[qt] = *(const bf16x8*)(qbuf + swzb(16 * qt + lo, hc + colq));
#pragma unroll
    for (int kc = 0; kc < 2; ++kc) {
      bf16x8 kf0 = *(const bf16x8*)(kbuf + swzb(16 * (2 * kc) + lo, hc + colq));
      bf16x8 kf1 = *(const bf16x8*)(kbuf + swzb(16 * (2 * kc + 1) + lo, hc + colq));
      f32x4 st0[4], st1[4];
#pragma unroll
      for (int qt = 0; qt < 4; ++qt) {
        st0[qt] = MFMA(kf0, qf[qt], zf);
        st1[qt] = MFMA(kf1, qf[qt], zf);
      }
#pragma unroll
      for (int qt = 0; qt < 4; ++qt)
#pragma unroll
        for (int r = 0; r < 4; ++r) {
          float p0 = exp2f(st0[qt][r]);
          float p1 = exp2f(st1[qt][r]);
          st0[qt][r] = p0; st1[qt][r] = p1;
          ls[hh][qt] += p0 + p1;
        }
      bf16x8 vf;
#pragma unroll
      for (int i = 0; i < 8; ++i) {
        int key = 32 * kc + 16 * (i >> 2) + 4 * hi + (i & 3);
        vf[i] = *(const short*)(vbuf + swzb(key, hc + lo));
      }
#pragma unroll
      for (int qt = 0; qt < 4; ++qt) {
        bf16x8 pa;
#pragma unroll
        for (int r = 0; r < 4; ++r) {
          pa[r] = f2bfs(st0[qt][r]);
          pa[4 + r] = f2bfs(st1[qt][r]);
        }
        o[hh][qt] = MFMA(pa, vf, o[hh][qt]);
      }
    }
  }
}

DEVI void outproj(const char* abuf, const short* __restrict__ wmat,
                  int w, int lo, int hi, f32x4* acc) {
#pragma unroll
  for (int kc = 0; kc < 4; ++kc) {
    bf16x8 a = *(const bf16x8*)(abuf + swzb(16 * w + lo, 32 * kc + 8 * hi));
#pragma unroll
    for (int ct = 0; ct < 8; ++ct) {
      bf16x8 bf = *(const bf16x8*)(wmat + (16 * ct + lo) * 128 + 32 * kc + 8 * hi);
      acc[ct] = MFMA(a, bf, acc[ct]);
    }
  }
}

// -------------------------------------------------------------- k_fused_t ----
__global__ void __launch_bounds__(256) k_fused_t(
    const float* __restrict__ x, const short* __restrict__ wcat,
    const float* __restrict__ biasin,
    short* __restrict__ sq, short* __restrict__ sk, short* __restrict__ sv,
    uint4* __restrict__ ot) {
  __shared__ uint4 smv[3072];  // 48 KiB
  char* bufX = (char*)smv;     // x -> t_v
  char* bufQ = bufX + 16384;   // t_q -> O_t stage
  char* bufK = bufX + 32768;   // t_k
  const int bm = blockIdx.x, b = bm >> 8, m = bm & 255;
  const int tid = threadIdx.x;

#pragma unroll
  for (int it = 0; it < 8; ++it) {
    int li = it * 256 + tid;
    int row = li >> 5, c4 = li & 31;
    float4 v = reinterpret_cast<const float4*>(x)[(size_t)((b * 64 + row) * 256 + m) * 32 + c4];
    short4v s;
    s[0] = f2bfs(v.x); s[1] = f2bfs(v.y); s[2] = f2bfs(v.z); s[3] = f2bfs(v.w);
    *(short4v*)(bufX + swzb(row, c4 * 4)) = s;
  }
  __syncthreads();

  const int w = tid >> 6, lane = tid & 63, lo = lane & 15, hi = lane >> 4;
  const int colq = 8 * (hi & 1);
  const f32x4 zf = {0.f, 0.f, 0.f, 0.f};

  bf16x8 af[4][4];
#pragma unroll
  for (int kc = 0; kc < 4; ++kc)
#pragma unroll
    for (int rt = 0; rt < 4; ++rt)
      af[kc][rt] = *(const bf16x8*)(bufX + swzb(16 * rt + lo, 32 * kc + 8 * hi));
  __syncthreads();

#pragma unroll
  for (int p = 0; p < 6; ++p) {
#pragma unroll
    for (int j = 0; j < 2; ++j) {
      int ct = 2 * w + j;
      f32x4 a4[4] = {zf, zf, zf, zf};
#pragma unroll
      for (int kc = 0; kc < 4; ++kc) {
        bf16x8 bcol = *(const bf16x8*)(wcat + (p * 128 + 16 * ct + lo) * 128 + 32 * kc + 8 * hi);
#pragma unroll
        for (int rt = 0; rt < 4; ++rt) a4[rt] = MFMA(af[kc][rt], bcol, a4[rt]);
      }
      float bb = biasin[p * 128 + 16 * ct + lo];
      if (p < 3) {
        char* pb = (p == 0) ? bufQ : (p == 1) ? bufK : bufX;
        float sc = (p == 0) ? QSCALE : 1.0f;
#pragma unroll
        for (int rt = 0; rt < 4; ++rt)
#pragma unroll
          for (int r = 0; r < 4; ++r)
            *(short*)(pb + swzb(16 * rt + 4 * hi + r, 16 * ct + lo)) =
                f2bfs((a4[rt][r] + bb) * sc);
      } else {
        short* dst = (p == 3) ? sq : (p == 4) ? sk : sv;
        float sc = (p == 3) ? QSCALE : 1.0f;
#pragma unroll
        for (int rt = 0; rt < 4; ++rt)
#pragma unroll
          for (int r = 0; r < 4; ++r)
            dst[(size_t)(bm * 64 + 16 * rt + 4 * hi + r) * 128 + 16 * ct + lo] =
                f2bfs((a4[rt][r] + bb) * sc);
      }
    }
  }
  __syncthreads();

  f32x4 o_t[2][4];
  float ls_t[2][4];
#pragma unroll
  for (int hh = 0; hh < 2; ++hh)
#pragma unroll
    for (int qt = 0; qt < 4; ++qt) { o_t[hh][qt] = zf; ls_t[hh][qt] = 0.f; }
  attn_block(bufQ, bufK, bufX, w, lo, hi, colq, o_t, ls_t);
  __syncthreads();

#pragma unroll
  for (int hh = 0; hh < 2; ++hh) {
    const int hc = (2 * w + hh) * 16;
#pragma unroll
    for (int qt = 0; qt < 4; ++qt) {
      float l = ls_t[hh][qt];
      l += __shfl_xor(l, 16);
      l += __shfl_xor(l, 32);
      float linv = 1.0f / l;
#pragma unroll
      for (int r = 0; r < 4; ++r) {
        float lr = __shfl(linv, 4 * hi + r);
        *(short*)(bufQ + swzb(16 * qt + 4 * hi + r, hc + lo)) = f2bfs(o_t[hh][qt][r] * lr);
      }
    }
  }
  __syncthreads();
#pragma unroll
  for (int it = 0; it < 4; ++it) {
    int li = it * 256 + tid;
    ot[(size_t)bm * 1024 + li] = *(const uint4*)(bufQ + swzb(li >> 4, (li & 15) * 8));
  }
}

// --------------------------------------------------------------- k_attn_s ----
// Wave w of block bm = head-pair w (dims w*32..w*32+32). Per-wave LDS 12800B:
//   Kbuf0 @0, Kbuf1 @4096  : slot-major K[slot s=2hh+hi1][key]16B (async-filled)
//   V     @8192            : [64 key][72B-stride rows] (conflict-free u16 reads)
// No barriers until the final cooperative store.
__global__ void __launch_bounds__(256, 3) k_attn_s(
    const short* __restrict__ sq, const short* __restrict__ skp,
    const short* __restrict__ svp, const int* __restrict__ route,
    uint4* __restrict__ os) {
  __shared__ char smem[51200];
  const int bm = blockIdx.x, b = bm >> 8, m = bm & 255;
  const int tid = threadIdx.x;
  const int w = tid >> 6, l = tid & 63;
  const int lo = l & 15, hi = l >> 4, hi1 = hi & 1;
  char* wbase = smem + w * 12800;
  const unsigned wb = ldsoff(wbase);
  const uint4* svp4 = (const uint4*)svp;
  const f32x4 zf = {0.f, 0.f, 0.f, 0.f};

  // Q fragments (this head-pair's 32-dim slice), loaded once from global
  bf16x8 qf[2][4];
#pragma unroll
  for (int hh = 0; hh < 2; ++hh)
#pragma unroll
    for (int qt = 0; qt < 4; ++qt)
      qf[hh][qt] = *(const bf16x8*)(sq + (size_t)(bm * 64 + 16 * qt + lo) * 128 +
                                    w * 32 + hh * 16 + 8 * hi1);

  uint4 pv[4];

  // K: 4 async 16B loads -> slot-major LDS (dst = base + lane*16, lane = key)
#define ISSUEK(BUF, NB)                                                       \
  do {                                                                        \
    const char* kb = (const char*)skp +                                       \
                     ((size_t)((b * 256 + (NB)) * 64 + l)) * 256 + w * 64;    \
    _Pragma("unroll") for (int s = 0; s < 4; ++s)                             \
        gload16(kb + s * 16, wb + (BUF)*4096 + s * 1024);                     \
  } while (0)

  // V: 4x16B -> regs
#define ISSUEV(NB)                                                            \
  do {                                                                        \
    size_t rb = ((size_t)((b * 256 + (NB)) * 64 + l)) * 16 + w * 4;           \
    _Pragma("unroll") for (int s = 0; s < 4; ++s) pv[s] = svp4[rb + s];       \
  } while (0)

  // V regs -> stride-72 rows (2 x b64 per 16B; 8B-aligned)
#define WRITEV()                                                              \
  do {                                                                        \
    _Pragma("unroll") for (int s = 0; s < 4; ++s) {                           \
      char* p = wbase + 8192 + l * 72 + s * 16;                               \
      *(unsigned long long*)p =                                               \
          ((unsigned long long)pv[s].y << 32) | pv[s].x;                      \
      *(unsigned long long*)(p + 8) =                                         \
          ((unsigned long long)pv[s].w << 32) | pv[s].z;                      \
    }                                                                         \
  } while (0)

  int nb = route[m * 4 + 0];
  ISSUEK(0, nb);
  ISSUEV(nb);
  __builtin_amdgcn_sched_barrier(0);
  asm volatile("s_waitcnt vmcnt(0)" ::: "memory");
  WRITEV();

  f32x4 o[2][4];
  float ls[2][4];
#pragma unroll
  for (int hh = 0; hh < 2; ++hh)
#pragma unroll
    for (int qt = 0; qt < 4; ++qt) { o[hh][qt] = zf; ls[hh][qt] = 0.f; }

#pragma unroll
  for (int c = 0; c < 4; ++c) {
    if (c < 3) {
      nb = route[m * 4 + c + 1];
      ISSUEK((c + 1) & 1, nb);  // async into other K buffer
      ISSUEV(nb);               // regs
      __builtin_amdgcn_sched_barrier(0);  // pin issue before compute
    }
    const char* kbuf = wbase + (c & 1) * 4096;
    const char* vbuf = wbase + 8192;
#pragma unroll
    for (int hh = 0; hh < 2; ++hh) {
      bf16x8 kf[4];
#pragma unroll
      for (int kt = 0; kt < 4; ++kt)
        kf[kt] = *(const bf16x8*)(kbuf + (2 * hh + hi1) * 1024 + (16 * kt + lo) * 16);
#pragma unroll
      for (int kc = 0; kc < 2; ++kc) {
        f32x4 st0[4], st1[4];
#pragma unroll
        for (int qt = 0; qt < 4; ++qt) {
          st0[qt] = MFMA(kf[2 * kc], qf[hh][qt], zf);
          st1[qt] = MFMA(kf[2 * kc + 1], qf[hh][qt], zf);
        }
#pragma unroll
        for (int qt = 0; qt < 4; ++qt)
#pragma unroll
          for (int r = 0; r < 4; ++r) {
            float p0 = exp2f(st0[qt][r]);
            float p1 = exp2f(st1[qt][r]);
            st0[qt][r] = p0; st1[qt][r] = p1;
            ls[hh][qt] += p0 + p1;
          }
        bf16x8 vf;
#pragma unroll
        for (int i = 0; i < 8; ++i) {
          int key = 32 * kc + 16 * (i >> 2) + 4 * hi + (i & 3);
          vf[i] = *(const short*)(vbuf + key * 72 + (hh * 16 + lo) * 2);
        }
#pragma unroll
        for (int qt = 0; qt < 4; ++qt) {
          bf16x8 pa;
#pragma unroll
          for (int r = 0; r < 4; ++r) {
            pa[r] = f2bfs(st0[qt][r]);
            pa[4 + r] = f2bfs(st1[qt][r]);
          }
          o[hh][qt] = MFMA(pa, vf, o[hh][qt]);
        }
      }
    }
    if (c < 3) {
      // K(c+1) must be fully in LDS before next chunk's reads; pv ready for write
      asm volatile("s_waitcnt vmcnt(0)" ::: "memory");
      WRITEV();  // same-wave DS order: V(c) reads above already served
    }
  }

  // normalize + stage O slice [64 q][64B] into V region (V reads done)
#pragma unroll
  for (int hh = 0; hh < 2; ++hh)
#pragma unroll
    for (int qt = 0; qt < 4; ++qt) {
      float lsum = ls[hh][qt];
      lsum += __shfl_xor(lsum, 16);
      lsum += __shfl_xor(lsum, 32);
      float linv = 1.0f / lsum;
#pragma unroll
      for (int r = 0; r < 4; ++r) {
        float lr = __shfl(linv, 4 * hi + r);
        *(short*)(wbase + 8192 + (16 * qt + 4 * hi + r) * 64 + (hh * 16 + lo) * 2) =
            f2bfs(o[hh][qt][r] * lr);
      }
    }
  __syncthreads();  // all waves staged -> block-coop full-line store
#pragma unroll
  for (int it = 0; it < 4; ++it) {
    int li = it * 256 + tid;               // row = li>>4, q16 = li&15
    int row = li >> 4, q16 = li & 15;
    const char* src = smem + (q16 >> 2) * 12800 + 8192 + row * 64 + (q16 & 3) * 16;
    os[(size_t)bm * 1024 + li] = *(const uint4*)src;
  }
#undef ISSUEK
#undef ISSUEV
#undef WRITEV
}

// ----------------------------------------------------------------- k_comb ----
__global__ void __launch_bounds__(256) k_comb(
    const uint4* __restrict__ ot, const uint4* __restrict__ os,
    const short* __restrict__ wto, const short* __restrict__ wso,
    const float* __restrict__ biasc, float* __restrict__ out) {
  __shared__ uint4 smv[2048];  // 32 KiB
  char* bufT = (char*)smv;
  char* bufS = bufT + 16384;
  const int bm = blockIdx.x, b = bm >> 8, m = bm & 255;
  const int tid = threadIdx.x;
#pragma unroll
  for (int it = 0; it < 4; ++it) {
    int li = it * 256 + tid;
    int o_ = swzb(li >> 4, (li & 15) * 8);
    *(uint4*)(bufT + o_) = ot[(size_t)bm * 1024 + li];
    *(uint4*)(bufS + o_) = os[(size_t)bm * 1024 + li];
  }
  __syncthreads();
  const int w = tid >> 6, lane = tid & 63, lo = lane & 15, hi = lane >> 4;
  const f32x4 zf = {0.f, 0.f, 0.f, 0.f};
  f32x4 accT[8], accS[8];
#pragma unroll
  for (int ct = 0; ct < 8; ++ct) { accT[ct] = zf; accS[ct] = zf; }
  outproj(bufT, wto, w, lo, hi, accT);
  outproj(bufS, wso, w, lo, hi, accS);
#pragma unroll
  for (int ct = 0; ct < 8; ++ct) {
    float bb = biasc[16 * ct + lo];
#pragma unroll
    for (int r = 0; r < 4; ++r) {
      int t = 16 * w + 4 * hi + r;
      out[(size_t)((b * 64 + t) * 256 + m) * 128 + 16 * ct + lo] =
          accT[ct][r] + accS[ct][r] + bb;
    }
  }
}

// ---------------------------------------------------------------- launch ----
extern "C" void kernel_launch(void* const* d_in, const int* in_sizes, int n_in,
                              void* d_out, int out_size, void* d_ws, size_t ws_size,
                              hipStream_t stream) {
  (void)in_sizes; (void)n_in; (void)out_size; (void)ws_size;
  const float* x = (const float*)d_in[0];
  const int* route = (const int*)d_in[1];
  const float* twin = (const float*)d_in[2];
  const float* tbin = (const float*)d_in[3];
  const float* twout = (const float*)d_in[4];
  const float* tbout = (const float*)d_in[5];
  const float* swin = (const float*)d_in[6];
  const float* sbin = (const float*)d_in[7];
  const float* swout = (const float*)d_in[8];
  const float* sbout = (const float*)d_in[9];

  char* ws = (char*)d_ws;
  size_t off = 0;
  auto alloc = [&](size_t bytes) {
    char* p = ws + off;
    off += (bytes + 255) & ~(size_t)255;
    return p;
  };
  short* wcat = (short*)alloc(768 * 128 * 2);
  float* biasin = (float*)alloc(768 * 4);
  short* wto = (short*)alloc(128 * 128 * 2);
  short* wso = (short*)alloc(128 * 128 * 2);
  float* biasc = (float*)alloc(128 * 4);
  short* sq = (short*)alloc((size_t)65536 * 128 * 2);
  short* sk = (short*)alloc((size_t)65536 * 128 * 2);
  short* sv = (short*)alloc((size_t)65536 * 128 * 2);
  uint4* ot = (uint4*)alloc((size_t)65536 * 128 * 2);
  uint4* os = (uint4*)alloc((size_t)65536 * 128 * 2);
  float* out = (float*)d_out;

  k_prep<<<dim3(64), dim3(256), 0, stream>>>(twin, tbin, twout, tbout, swin, sbin,
                                             swout, sbout, wcat, biasin, wto, wso, biasc);
  k_fused_t<<<dim3(1024), dim3(256), 0, stream>>>(x, wcat, biasin, sq, sk, sv, ot);
  k_attn_s<<<dim3(1024), dim3(256), 0, stream>>>(sq, sk, sv, route, os);
  k_comb<<<dim3(1024), dim3(256), 0, stream>>>(ot, os, wto, wso, biasc, out);
}